// Round 7
// baseline (334.683 us; speedup 1.0000x reference)
//
#include <hip/hip_runtime.h>

// ---------------------------------------------------------------------------
// EMLLocalMessageBlock on MI355X — round 7 (round 6 + 640-thread-loop fix).
//   h = center@Wc + A_n2@Wn + pre ; drive/res = gelu(h)@w2 ; gate = EML(d,r)
//   update = Sum_n (g_n/mass)(A_n @ VoW) + (vb@oW)*(sg/mass) + ob
// K-permutation (torch-reshape scramble): slot k'=16r+t <-> c2 = r+9t; r = ks.
// Weights pre-folded FRAGMENT-MAJOR (per (col-tile,ks): 512 bf16 = one
// coalesced dwordx4/lane wave load). Lessons: >8-wave blocks or P1+P2 fused
// exceed the 128-reg cap at 4 waves/SIMD and SPILL. Two kernels, each
// __launch_bounds__(512,4) -> 2 blocks/CU, 4 waves/SIMD, <=43 KB LDS.
// ROUND-6 BUG: g10 emit/stage used `if (tid<640)` in 512-thread blocks ->
// px 52..63 of every block got poison gates. Now grid-stride loops.
// ---------------------------------------------------------------------------

#define USHORT unsigned short
#define AW 152   // LDS A row stride elems (304 B = 76 dw = 12 mod 32: conflict-free)

typedef __attribute__((ext_vector_type(8)))  __bf16 v8bf;
typedef __attribute__((ext_vector_type(8)))  USHORT v8u;
typedef __attribute__((ext_vector_type(16))) float  v16f;

__device__ __forceinline__ float bflo(unsigned u) {
    unsigned v = u << 16; float f; __builtin_memcpy(&f, &v, 4); return f;
}
__device__ __forceinline__ float bfhi(unsigned u) {
    unsigned v = u & 0xffff0000u; float f; __builtin_memcpy(&f, &v, 4); return f;
}
__device__ __forceinline__ USHORT f2bf(float f) {
    unsigned v; __builtin_memcpy(&v, &f, 4);
    v += 0x7FFFu + ((v >> 16) & 1u);
    return (USHORT)(v >> 16);
}

// ---------------------------------------------------------------------------
// k_setup: [0,1024) LN1 (32 px/block); then weight fold into frag layouts.
// ---------------------------------------------------------------------------
__global__ __launch_bounds__(256) void k_setup(
    const float* __restrict__ tok, const float* __restrict__ ln1g,
    const float* __restrict__ ln1b,
    const float* __restrict__ dW1, const float* __restrict__ db1,
    const float* __restrict__ rW1, const float* __restrict__ rb1,
    const float* __restrict__ rel, const float* __restrict__ dW2,
    const float* __restrict__ rW2, const float* __restrict__ vW,
    const float* __restrict__ vb,  const float* __restrict__ oW,
    USHORT* __restrict__ norm, USHORT* __restrict__ WnF,
    USHORT* __restrict__ WcF, USHORT* __restrict__ VF,
    float* __restrict__ preF, float* __restrict__ vboW, float* __restrict__ w2g)
{
    __shared__ float oWs[4096];
    const int blk = blockIdx.x, t = threadIdx.x;
    if (blk < 1024) {                     // ---- LN1: 32 px ----
        const int lane = t & 63, wv = t >> 6;
        for (int i = 0; i < 8; ++i) {
            const int p = blk * 32 + wv * 8 + i;
            const float2 x = ((const float2*)(tok + (size_t)p * 128))[lane];
            float s = x.x + x.y;
            for (int m = 1; m < 64; m <<= 1) s += __shfl_xor(s, m);
            const float mean = s * (1.f / 128.f);
            const float d0 = x.x - mean, d1 = x.y - mean;
            float q = d0 * d0 + d1 * d1;
            for (int m = 1; m < 64; m <<= 1) q += __shfl_xor(q, m);
            const float rstd = rsqrtf(q * (1.f / 128.f) + 1e-5f);
            const float2 gg = ((const float2*)ln1g)[lane], bb = ((const float2*)ln1b)[lane];
            ((unsigned*)norm)[(size_t)p * 64 + lane] =
                (unsigned)f2bf(d0 * rstd * gg.x + bb.x) |
                ((unsigned)f2bf(d1 * rstd * gg.y + bb.y) << 16);
        }
        return;
    }
    const int b2 = blk - 1024;
    const int p2 = 2 * t, L = p2 >> 3, j0 = p2 & 7;
    const int l31 = L & 31, hif = L >> 5;
    if (b2 < 72) {                        // WnF[cg(8)][ks(9)]: perm (W1b-W1c)^T
        int cg = (b2 * 7282) >> 16;       // /9
        int ks = b2 - 9 * cg;
        int h = (cg & 3) * 32 + l31;
        const float* W = (cg < 4) ? dW1 : rW1;
        USHORT o[2];
        #pragma unroll
        for (int jj = 0; jj < 2; ++jj) {
            int tt = hif * 8 + j0 + jj;
            int c2 = ks + 9 * tt;
            float val = 0.f;
            if (c2 < 128) val = W[(128 + c2) * 128 + h] - W[(256 + c2) * 128 + h];
            o[jj] = f2bf(val);
        }
        *(unsigned*)(WnF + b2 * 512 + p2) = (unsigned)o[0] | ((unsigned)o[1] << 16);
    } else if (b2 < 136) {                // WcF[cg(8)][ks(8)]: (W1a+W1c)^T natural K
        int pr = b2 - 72;
        int cg = pr >> 3, ks = pr & 7;
        int h = (cg & 3) * 32 + l31;
        const float* W = (cg < 4) ? dW1 : rW1;
        USHORT o[2];
        #pragma unroll
        for (int jj = 0; jj < 2; ++jj) {
            int k = ks * 16 + hif * 8 + j0 + jj;
            o[jj] = f2bf(W[k * 128 + h] + W[(256 + k) * 128 + h]);
        }
        *(unsigned*)(WcF + pr * 512 + p2) = (unsigned)o[0] | ((unsigned)o[1] << 16);
    } else if (b2 < 172) {                // VF[cg(4)][ks(9)]: perm (vW@oW)^T
        int pr = b2 - 136;
        int cg = (pr * 7282) >> 16;
        int ks = pr - 9 * cg;
        for (int i = t; i < 4096; i += 256) {          // stage oW 32-col slice
            int j = i >> 5, nn = i & 31;
            oWs[i] = oW[j * 128 + cg * 32 + nn];
        }
        __syncthreads();
        USHORT o[2];
        #pragma unroll
        for (int jj = 0; jj < 2; ++jj) {
            int tt = hif * 8 + j0 + jj;
            int c2 = ks + 9 * tt;
            float acc = 0.f;
            if (c2 < 128)
                for (int j = 0; j < 128; ++j) acc += vW[c2 * 128 + j] * oWs[j * 32 + l31];
            o[jj] = f2bf(acc);
        }
        *(unsigned*)(VF + pr * 512 + p2) = (unsigned)o[0] | ((unsigned)o[1] << 16);
    } else if (b2 < 181) {                // preF[9][256] = rel@W1d + b1
        int n2 = b2 - 172, h = t;
        float acc;
        if (h < 128) {
            acc = db1[h];
            for (int r = 0; r < 8; ++r) acc += rel[n2 * 8 + r] * dW1[(384 + r) * 128 + h];
        } else {
            int hh = h - 128;
            acc = rb1[hh];
            for (int r = 0; r < 8; ++r) acc += rel[n2 * 8 + r] * rW1[(384 + r) * 128 + hh];
        }
        preF[n2 * 256 + h] = acc;
    } else {
        if (t < 128) {
            float acc = 0.f;
            for (int j = 0; j < 128; ++j) acc += vb[j] * oW[j * 128 + t];
            vboW[t] = acc;
            w2g[t] = dW2[t];
            w2g[128 + t] = rW2[t];
        }
    }
}

// ---------------------------------------------------------------------------
// gather helpers: thread (gx = tid>>3, gq = tid&7) loads one dword
// (2 channels) per residue r; loads issued first, then parity-merge.
// ---------------------------------------------------------------------------
__device__ __forceinline__ void gather_load(
    unsigned gv[9], const USHORT* __restrict__ nb,
    int n2, int y, int xg, int bI, int gq)
{
    #pragma unroll
    for (int r = 0; r < 9; ++r) {
        int u = 2 * n2 + r;
        int n = (u >= 18) ? (u - 18) : ((u >= 9) ? (u - 9) : u);
        int v = n2 * 128 + r;
        int c0 = (v * 7282) >> 16;                 // v/9
        int dyq = (n * 22) >> 6;                   // n/3
        int dx = n - 3 * dyq - 1, dy = dyq - 1;
        int sy = y + dy, sx = xg + dx;
        bool ok = ((unsigned)sy < 128u) && ((unsigned)sx < 128u);
        int e0 = (c0 & ~1) + 2 * gq;
        size_t gidx = ((size_t)((bI * 128 + (ok ? sy : 0)) * 128 + (ok ? sx : 0))) * 128 + e0;
        gv[r] = ok ? ((const unsigned*)nb)[gidx >> 1] : 0u;
    }
    #pragma unroll
    for (int r = 0; r < 9; ++r) {                  // parity merge (slot15 = zero-wt)
        int v = n2 * 128 + r;
        int c0 = (v * 7282) >> 16;
        unsigned nxt = (unsigned)__shfl_down((int)gv[r], 1);
        if (c0 & 1) gv[r] = (gv[r] >> 16) | (nxt << 16);
    }
}
__device__ __forceinline__ void gather_store(
    USHORT* __restrict__ As, const unsigned gv[9], int gx, int gq)
{
    #pragma unroll
    for (int r = 0; r < 9; ++r)
        *(unsigned*)(As + gx * AW + 16 * r + 2 * gq) = gv[r];
}

// ---------------------------------------------------------------------------
// k_gate: 512 blocks x 512 thr, 64 px/block. wave = col-tile cg (4 drive,
// 4 res), 2 M-tiles each. Emits g10[px][10] bf16 = {g_n/mass x9, sg/mass}.
// MFMA 32x32x16 bf16; C/D: col=lane&31, row=(reg&3)+8*(reg>>2)+4*(lane>>5).
// ---------------------------------------------------------------------------
__global__ __launch_bounds__(512, 4) void k_gate(
    const USHORT* __restrict__ nb,
    const USHORT* __restrict__ WnF, const USHORT* __restrict__ WcF,
    const float* __restrict__ preF, const float* __restrict__ w2g,
    const float* __restrict__ db2p, const float* __restrict__ rb2p,
    const float* __restrict__ gmp, const float* __restrict__ lmp,
    const float* __restrict__ bip, USHORT* __restrict__ g10)
{
    __shared__ char smem[43008];
    USHORT* A0   = (USHORT*)smem;                    // [64][152] = 19456
    USHORT* A1   = (USHORT*)(smem + 19456);          // [64][152] = 19456
    float*  S    = (float*)(smem + 38912);           // [3][128]  = 1536
    float*  gateL= (float*)(smem + 40448);           // [9][64]   = 2304
    float*  sgL  = (float*)(smem + 42752);           // [64]

    const int tid = threadIdx.x;
    const int lane = tid & 63, wave = tid >> 6, hi = lane >> 5, l31 = lane & 31;
    const int gx = tid >> 3, gq = tid & 7;
    const int blk = blockIdx.x;
    const int bI = blk >> 8, bb = blk & 255;
    const int half = bb & 1, yb = bb >> 1;
    const int y = ((yb & 7) << 4) | ((yb >> 3) & 15);     // XCD band swizzle
    const int xg = half * 64 + gx;
    const int px0 = (bI * 128 + y) * 128 + half * 64;

    // ---- stage own 64 px (K natural) -> A1; zero sums ----
    for (int i = tid; i < 1024; i += 512) {
        int x = i >> 4, kv = i & 15;
        *(v8u*)(A1 + x * AW + kv * 8) = *(const v8u*)(nb + (size_t)(px0 + x) * 128 + kv * 8);
    }
    if (tid < 384) S[tid] = 0.f;
    if (tid < 64) sgL[tid] = 0.f;
    __syncthreads();

    // ---- center GEMM (K=128) -> packed bf16 pairs (Mtile0, Mtile1) ----
    const int cg = wave;
    v16f c0a, c1a;
    #pragma unroll
    for (int e = 0; e < 16; ++e) { c0a[e] = 0.f; c1a[e] = 0.f; }
    #pragma unroll
    for (int ks = 0; ks < 8; ++ks) {
        v8bf a0 = *(const v8bf*)(A1 + l31 * AW + ks * 16 + hi * 8);
        v8bf a1 = *(const v8bf*)(A1 + (32 + l31) * AW + ks * 16 + hi * 8);
        v8bf bf = *(const v8bf*)(WcF + ((cg << 3) + ks) * 512 + lane * 8);
        c0a = __builtin_amdgcn_mfma_f32_32x32x16_bf16(a0, bf, c0a, 0, 0, 0);
        c1a = __builtin_amdgcn_mfma_f32_32x32x16_bf16(a1, bf, c1a, 0, 0, 0);
    }
    unsigned cpk[16];
    #pragma unroll
    for (int e = 0; e < 16; ++e)
        cpk[e] = (unsigned)f2bf(c0a[e]) | ((unsigned)f2bf(c1a[e]) << 16);

    {   // first gather -> A0
        unsigned gv[9];
        gather_load(gv, nb, 0, y, xg, bI, gq);
        gather_store(A0, gv, gx, gq);
    }
    // persistent B-frags (n2-invariant): 9 x 4 VGPR
    v8bf Bp[9];
    #pragma unroll
    for (int ks = 0; ks < 9; ++ks)
        Bp[ks] = *(const v8bf*)(WnF + (cg * 9 + ks) * 512 + lane * 8);
    __syncthreads();

    const float gmv = gmp[0], lmv = lmp[0], biv = bip[0];
    const float db2v = db2p[0], rb2v = rb2p[0];
    const float wv = w2g[cg * 32 + l31];
    const int tgt_off = (cg >= 4) ? 64 : 0;
    const int rbase = 4 * hi;

    for (int n2 = 0; n2 < 9; ++n2) {
        const float pre = preF[n2 * 256 + cg * 32 + l31];
        unsigned gv[9];
        if (n2 < 8) gather_load(gv, nb, n2 + 1, y, xg, bI, gq);

        USHORT* Ac = (n2 & 1) ? A1 : A0;
        USHORT* An = (n2 & 1) ? A0 : A1;
        v16f ad0, ad1;
        #pragma unroll
        for (int e = 0; e < 16; ++e) { ad0[e] = 0.f; ad1[e] = 0.f; }
        #pragma unroll
        for (int ks = 0; ks < 9; ++ks) {
            v8bf a0 = *(const v8bf*)(Ac + l31 * AW + ks * 16 + hi * 8);
            v8bf a1 = *(const v8bf*)(Ac + (32 + l31) * AW + ks * 16 + hi * 8);
            ad0 = __builtin_amdgcn_mfma_f32_32x32x16_bf16(a0, Bp[ks], ad0, 0, 0, 0);
            ad1 = __builtin_amdgcn_mfma_f32_32x32x16_bf16(a1, Bp[ks], ad1, 0, 0, 0);
        }
        float* Sset = S + (n2 % 3) * 128 + tgt_off;
        #pragma unroll
        for (int c4 = 0; c4 < 4; ++c4) {
            float z4[4];
            #pragma unroll
            for (int k4 = 0; k4 < 4; ++k4) {
                int rr = c4 * 4 + k4;
                float h0 = ad0[rr] + pre + bflo(cpk[rr]);
                float h1 = ad1[rr] + pre + bfhi(cpk[rr]);
                float p0 = h0 * __builtin_amdgcn_rcpf(1.f + __expf(-1.702f * h0)) * wv;
                float p1 = h1 * __builtin_amdgcn_rcpf(1.f + __expf(-1.702f * h1)) * wv;
                float sa = p0 + __shfl_xor(p0, 1);     // even lanes: M-tile0
                float sb = p1 + __shfl_xor(p1, 1);     // odd lanes:  M-tile1
                z4[k4] = (l31 & 1) ? sb : sa;
            }
            #pragma unroll
            for (int m = 2; m < 32; m <<= 1) {
                #pragma unroll
                for (int k4 = 0; k4 < 4; ++k4) z4[k4] += __shfl_xor(z4[k4], m);
            }
            if (l31 < 2) {
                int rb = rbase + 8 * c4 + ((l31 == 1) ? 32 : 0);
                #pragma unroll
                for (int k4 = 0; k4 < 4; ++k4)
                    atomicAdd(&Sset[rb + k4], z4[k4]);
            }
        }
        if (n2 < 8) gather_store(An, gv, gx, gq);
        __syncthreads();
        // gates (wave0) + zero set 2-ahead (threads 64..191)
        if (tid < 64) {
            float d = S[(n2 % 3) * 128 + tid] + db2v;
            float r = S[(n2 % 3) * 128 + 64 + tid] + rb2v;
            float sp = fmaxf(r, 0.f) + log1pf(__expf(-fabsf(r)));
            float e = gmv * d / (lmv * sp + 1e-6f) + biv;
            e = fminf(fmaxf(e, -3.f), 3.f);
            float gt = 1.f / (1.f + __expf(-e));
            gateL[n2 * 64 + tid] = gt;
            sgL[tid] += gt;
        } else if (tid < 192) {
            S[((n2 + 2) % 3) * 128 + tid - 64] = 0.f;
        }
    }
    __syncthreads();

    if (tid < 64) {
        float s = sgL[tid];
        float m = fmaxf(s, 1e-6f);
        S[tid] = 1.f / m;                 // 1/mass
        S[64 + tid] = s / m;              // sg/mass
    }
    __syncthreads();
    for (int i = tid; i < 640; i += 512) {           // FIX: grid-stride, not if<640
        int px = (i * 6554) >> 16;        // i/10
        int n = i - px * 10;
        float val = (n < 9) ? gateL[n * 64 + px] * S[px] : S[64 + px];
        g10[(size_t)(px0 + px) * 10 + n] = f2bf(val);
    }
}

// ---------------------------------------------------------------------------
// k_msg: 512 blocks x 512 thr, 64 px/block. wave = (mwp, nwp): 2M x 4N.
// acc3 = Sum_n (g_n/mass)(A_n @ VoW); update + fused LN2.
// ---------------------------------------------------------------------------
__global__ __launch_bounds__(512, 4) void k_msg(
    const float* __restrict__ tok, const float* __restrict__ ln2g,
    const float* __restrict__ ln2b, const USHORT* __restrict__ nb,
    const USHORT* __restrict__ VF, const float* __restrict__ vboW,
    const float* __restrict__ obp, const USHORT* __restrict__ g10,
    float* __restrict__ out)
{
    __shared__ char smem[41472];
    USHORT* A0   = (USHORT*)smem;                    // [64][152] = 19456
    USHORT* A1   = (USHORT*)(smem + 19456);          // [64][152] = 19456
    float*  gL   = (float*)(smem + 38912);           // [9][64] gates + [64] sgm
    float*  updF = (float*)smem;                     // tail alias [64][128] f32

    const int tid = threadIdx.x;
    const int lane = tid & 63, wave = tid >> 6, hi = lane >> 5, l31 = lane & 31;
    const int mwp = wave & 1, nwp = wave >> 1;
    const int gx = tid >> 3, gq = tid & 7;
    const int blk = blockIdx.x;
    const int bI = blk >> 8, bb = blk & 255;
    const int half = bb & 1, yb = bb >> 1;
    const int y = ((yb & 7) << 4) | ((yb >> 3) & 15);
    const int xg = half * 64 + gx;
    const int px0 = (bI * 128 + y) * 128 + half * 64;

    // ---- stage gates (grid-stride FIX) + first gather ----
    for (int i = tid; i < 640; i += 512) {
        int px = (i * 6554) >> 16;
        int n = i - px * 10;
        gL[n * 64 + px] = bflo((unsigned)g10[(size_t)(px0 + px) * 10 + n]);
    }
    {
        unsigned gv[9];
        gather_load(gv, nb, 0, y, xg, bI, gq);
        gather_store(A0, gv, gx, gq);
    }
    v8bf Vp[9];
    #pragma unroll
    for (int ks = 0; ks < 9; ++ks)
        Vp[ks] = *(const v8bf*)(VF + (nwp * 9 + ks) * 512 + lane * 8);
    __syncthreads();

    v16f acc3;
    #pragma unroll
    for (int e = 0; e < 16; ++e) acc3[e] = 0.f;

    for (int m2 = 0; m2 < 9; ++m2) {
        unsigned gv[9];
        if (m2 < 8) gather_load(gv, nb, m2 + 1, y, xg, bI, gq);
        USHORT* Ac = (m2 & 1) ? A1 : A0;
        USHORT* An = (m2 & 1) ? A0 : A1;
        v16f am;
        #pragma unroll
        for (int e = 0; e < 16; ++e) am[e] = 0.f;
        #pragma unroll
        for (int ks = 0; ks < 9; ++ks) {
            v8bf a = *(const v8bf*)(Ac + (mwp * 32 + l31) * AW + ks * 16 + hi * 8);
            am = __builtin_amdgcn_mfma_f32_32x32x16_bf16(a, Vp[ks], am, 0, 0, 0);
        }
        {   // acc3 += (g/mass)(m2) ⊙ am
            const float4* gq4 = (const float4*)(gL + m2 * 64 + mwp * 32 + 4 * hi);
            float4 ga = gq4[0], gb = gq4[2], gc = gq4[4], gd = gq4[6];
            float gs[16] = {ga.x, ga.y, ga.z, ga.w, gb.x, gb.y, gb.z, gb.w,
                            gc.x, gc.y, gc.z, gc.w, gd.x, gd.y, gd.z, gd.w};
            #pragma unroll
            for (int rr = 0; rr < 16; ++rr) acc3[rr] += gs[rr] * am[rr];
        }
        if (m2 < 8) gather_store(An, gv, gx, gq);
        __syncthreads();
    }

    // ---- update + LN2 ----
    {
        const int col = nwp * 32 + l31;
        const float vbw = vboW[col], obv = obp[col];
        const int base = mwp * 32 + 4 * hi;
        const float4* sq = (const float4*)(gL + 576 + base);
        float4 sa = sq[0], sb = sq[2], sc = sq[4], sd = sq[6];
        float sv[16] = {sa.x, sa.y, sa.z, sa.w, sb.x, sb.y, sb.z, sb.w,
                        sc.x, sc.y, sc.z, sc.w, sd.x, sd.y, sd.z, sd.w};
        #pragma unroll
        for (int rr = 0; rr < 16; ++rr) {
            int row = base + (rr & 3) + 8 * (rr >> 2);
            updF[row * 128 + col] = acc3[rr] + vbw * sv[rr] + obv;
        }
    }
    __syncthreads();

    const float g20 = ln2g[lane], g21 = ln2g[lane + 64];
    const float b20 = ln2b[lane], b21 = ln2b[lane + 64];
    for (int q2 = 0; q2 < 8; ++q2) {
        int p = wave * 8 + q2;
        size_t gp = (size_t)(px0 + p) * 128;
        float x0 = tok[gp + lane]      + updF[p * 128 + lane];
        float x1 = tok[gp + lane + 64] + updF[p * 128 + lane + 64];
        float s = x0 + x1;
        for (int m = 1; m < 64; m <<= 1) s += __shfl_xor(s, m);
        float mean = s * (1.f / 128.f);
        float d0 = x0 - mean, d1 = x1 - mean;
        float qq = d0 * d0 + d1 * d1;
        for (int m = 1; m < 64; m <<= 1) qq += __shfl_xor(qq, m);
        float rstd = rsqrtf(qq * (1.f / 128.f) + 1e-5f);
        out[gp + lane]      = d0 * rstd * g20 + b20;
        out[gp + lane + 64] = d1 * rstd * g21 + b21;
    }
}

// ---------------------------------------------------------------------------
extern "C" void kernel_launch(void* const* d_in, const int* in_sizes, int n_in,
                              void* d_out, int out_size, void* d_ws, size_t ws_size,
                              hipStream_t stream) {
    const float* tok  = (const float*)d_in[0];
    const float* ln1g = (const float*)d_in[1];
    const float* ln1b = (const float*)d_in[2];
    const float* ln2g = (const float*)d_in[3];
    const float* ln2b = (const float*)d_in[4];
    const float* rel  = (const float*)d_in[5];
    const float* dW1  = (const float*)d_in[6];
    const float* db1  = (const float*)d_in[7];
    const float* dW2  = (const float*)d_in[8];
    const float* db2  = (const float*)d_in[9];
    const float* rW1  = (const float*)d_in[10];
    const float* rb1  = (const float*)d_in[11];
    const float* rW2  = (const float*)d_in[12];
    const float* rb2  = (const float*)d_in[13];
    const float* vW   = (const float*)d_in[14];
    const float* vb   = (const float*)d_in[15];
    const float* oW   = (const float*)d_in[16];
    const float* ob   = (const float*)d_in[17];
    const float* gm   = (const float*)d_in[18];
    const float* lm   = (const float*)d_in[19];
    const float* bi   = (const float*)d_in[20];
    float* out = (float*)d_out;

    char* w = (char*)d_ws;
    USHORT* norm = (USHORT*)w; w += 8388608;   // [32768][128] bf16
    USHORT* WnF  = (USHORT*)w; w += 73728;     // [72 frag-blocks][512] bf16
    USHORT* WcF  = (USHORT*)w; w += 65536;     // [64][512]
    USHORT* VF   = (USHORT*)w; w += 36864;     // [36][512]
    USHORT* g10  = (USHORT*)w; w += 655360;    // [32768][10] bf16 (g/mass, sgm)
    float*  preF = (float*)w;  w += 9216;      // [9][256] f32
    float*  vboW = (float*)w;  w += 512;       // [128]
    float*  w2g  = (float*)w;  w += 1024;      // [256]

    hipLaunchKernelGGL(k_setup, dim3(1206), dim3(256), 0, stream,
                       tok, ln1g, ln1b, dW1, db1, rW1, rb1, rel, dW2, rW2,
                       vW, vb, oW, norm, WnF, WcF, VF, preF, vboW, w2g);
    hipLaunchKernelGGL(k_gate, dim3(512), dim3(512), 0, stream,
                       norm, WnF, WcF, preF, w2g, db2, rb2, gm, lm, bi, g10);
    hipLaunchKernelGGL(k_msg, dim3(512), dim3(512), 0, stream,
                       tok, ln2g, ln2b, norm, VF, vboW, ob, g10, out);
}

// Round 8
// 266.924 us; speedup vs baseline: 1.2539x; 1.2539x over previous
//
#include <hip/hip_runtime.h>

// ---------------------------------------------------------------------------
// EMLLocalMessageBlock on MI355X — round 8 (round 7 + launch-bounds fix).
//   h = center@Wc + A_n2@Wn + pre ; drive/res = gelu(h)@w2 ; gate = EML(d,r)
//   update = Sum_n (g_n/mass)(A_n @ VoW) + (vb@oW)*(sg/mass) + ob
// K-permutation (torch-reshape scramble): slot k'=16r+t <-> c2 = r+9t; r = ks.
// Weights pre-folded FRAGMENT-MAJOR (per (col-tile,ks): 512 bf16 = one
// coalesced dwordx4/lane wave load).
// MEASURED LESSON (r3 vs r5/6/7): __launch_bounds__(512,4) makes the compiler
// split the unified file 64 arch + 64 AGPR and SPILL (450 MB scratch);
// (512,2) lands at ~110 regs, no spill, and HW still runs 4 waves/SIMD
// because the actual allocation is <=128. Never declare min-waves=4 here.
// ---------------------------------------------------------------------------

#define USHORT unsigned short
#define AW 152   // LDS A row stride elems (304 B = 76 dw = 12 mod 32: conflict-free)

typedef __attribute__((ext_vector_type(8)))  __bf16 v8bf;
typedef __attribute__((ext_vector_type(8)))  USHORT v8u;
typedef __attribute__((ext_vector_type(16))) float  v16f;

__device__ __forceinline__ float bflo(unsigned u) {
    unsigned v = u << 16; float f; __builtin_memcpy(&f, &v, 4); return f;
}
__device__ __forceinline__ float bfhi(unsigned u) {
    unsigned v = u & 0xffff0000u; float f; __builtin_memcpy(&f, &v, 4); return f;
}
__device__ __forceinline__ USHORT f2bf(float f) {
    unsigned v; __builtin_memcpy(&v, &f, 4);
    v += 0x7FFFu + ((v >> 16) & 1u);
    return (USHORT)(v >> 16);
}

// ---------------------------------------------------------------------------
// k_setup: [0,1024) LN1 (32 px/block); then weight fold into frag layouts.
// ---------------------------------------------------------------------------
__global__ __launch_bounds__(256) void k_setup(
    const float* __restrict__ tok, const float* __restrict__ ln1g,
    const float* __restrict__ ln1b,
    const float* __restrict__ dW1, const float* __restrict__ db1,
    const float* __restrict__ rW1, const float* __restrict__ rb1,
    const float* __restrict__ rel, const float* __restrict__ dW2,
    const float* __restrict__ rW2, const float* __restrict__ vW,
    const float* __restrict__ vb,  const float* __restrict__ oW,
    USHORT* __restrict__ norm, USHORT* __restrict__ WnF,
    USHORT* __restrict__ WcF, USHORT* __restrict__ VF,
    float* __restrict__ preF, float* __restrict__ vboW, float* __restrict__ w2g)
{
    __shared__ float oWs[4096];
    const int blk = blockIdx.x, t = threadIdx.x;
    if (blk < 1024) {                     // ---- LN1: 32 px ----
        const int lane = t & 63, wv = t >> 6;
        for (int i = 0; i < 8; ++i) {
            const int p = blk * 32 + wv * 8 + i;
            const float2 x = ((const float2*)(tok + (size_t)p * 128))[lane];
            float s = x.x + x.y;
            for (int m = 1; m < 64; m <<= 1) s += __shfl_xor(s, m);
            const float mean = s * (1.f / 128.f);
            const float d0 = x.x - mean, d1 = x.y - mean;
            float q = d0 * d0 + d1 * d1;
            for (int m = 1; m < 64; m <<= 1) q += __shfl_xor(q, m);
            const float rstd = rsqrtf(q * (1.f / 128.f) + 1e-5f);
            const float2 gg = ((const float2*)ln1g)[lane], bb = ((const float2*)ln1b)[lane];
            ((unsigned*)norm)[(size_t)p * 64 + lane] =
                (unsigned)f2bf(d0 * rstd * gg.x + bb.x) |
                ((unsigned)f2bf(d1 * rstd * gg.y + bb.y) << 16);
        }
        return;
    }
    const int b2 = blk - 1024;
    const int p2 = 2 * t, L = p2 >> 3, j0 = p2 & 7;
    const int l31 = L & 31, hif = L >> 5;
    if (b2 < 72) {                        // WnF[cg(8)][ks(9)]: perm (W1b-W1c)^T
        int cg = (b2 * 7282) >> 16;       // /9
        int ks = b2 - 9 * cg;
        int h = (cg & 3) * 32 + l31;
        const float* W = (cg < 4) ? dW1 : rW1;
        USHORT o[2];
        #pragma unroll
        for (int jj = 0; jj < 2; ++jj) {
            int tt = hif * 8 + j0 + jj;
            int c2 = ks + 9 * tt;
            float val = 0.f;
            if (c2 < 128) val = W[(128 + c2) * 128 + h] - W[(256 + c2) * 128 + h];
            o[jj] = f2bf(val);
        }
        *(unsigned*)(WnF + b2 * 512 + p2) = (unsigned)o[0] | ((unsigned)o[1] << 16);
    } else if (b2 < 136) {                // WcF[cg(8)][ks(8)]: (W1a+W1c)^T natural K
        int pr = b2 - 72;
        int cg = pr >> 3, ks = pr & 7;
        int h = (cg & 3) * 32 + l31;
        const float* W = (cg < 4) ? dW1 : rW1;
        USHORT o[2];
        #pragma unroll
        for (int jj = 0; jj < 2; ++jj) {
            int k = ks * 16 + hif * 8 + j0 + jj;
            o[jj] = f2bf(W[k * 128 + h] + W[(256 + k) * 128 + h]);
        }
        *(unsigned*)(WcF + pr * 512 + p2) = (unsigned)o[0] | ((unsigned)o[1] << 16);
    } else if (b2 < 172) {                // VF[cg(4)][ks(9)]: perm (vW@oW)^T
        int pr = b2 - 136;
        int cg = (pr * 7282) >> 16;
        int ks = pr - 9 * cg;
        for (int i = t; i < 4096; i += 256) {          // stage oW 32-col slice
            int j = i >> 5, nn = i & 31;
            oWs[i] = oW[j * 128 + cg * 32 + nn];
        }
        __syncthreads();
        USHORT o[2];
        #pragma unroll
        for (int jj = 0; jj < 2; ++jj) {
            int tt = hif * 8 + j0 + jj;
            int c2 = ks + 9 * tt;
            float acc = 0.f;
            if (c2 < 128)
                for (int j = 0; j < 128; ++j) acc += vW[c2 * 128 + j] * oWs[j * 32 + l31];
            o[jj] = f2bf(acc);
        }
        *(unsigned*)(VF + pr * 512 + p2) = (unsigned)o[0] | ((unsigned)o[1] << 16);
    } else if (b2 < 181) {                // preF[9][256] = rel@W1d + b1
        int n2 = b2 - 172, h = t;
        float acc;
        if (h < 128) {
            acc = db1[h];
            for (int r = 0; r < 8; ++r) acc += rel[n2 * 8 + r] * dW1[(384 + r) * 128 + h];
        } else {
            int hh = h - 128;
            acc = rb1[hh];
            for (int r = 0; r < 8; ++r) acc += rel[n2 * 8 + r] * rW1[(384 + r) * 128 + hh];
        }
        preF[n2 * 256 + h] = acc;
    } else {
        if (t < 128) {
            float acc = 0.f;
            for (int j = 0; j < 128; ++j) acc += vb[j] * oW[j * 128 + t];
            vboW[t] = acc;
            w2g[t] = dW2[t];
            w2g[128 + t] = rW2[t];
        }
    }
}

// ---------------------------------------------------------------------------
// gather helpers: thread (gx = tid>>3, gq = tid&7) loads one dword
// (2 channels) per residue r; loads issued first, then parity-merge.
// ---------------------------------------------------------------------------
__device__ __forceinline__ void gather_load(
    unsigned gv[9], const USHORT* __restrict__ nb,
    int n2, int y, int xg, int bI, int gq)
{
    #pragma unroll
    for (int r = 0; r < 9; ++r) {
        int u = 2 * n2 + r;
        int n = (u >= 18) ? (u - 18) : ((u >= 9) ? (u - 9) : u);
        int v = n2 * 128 + r;
        int c0 = (v * 7282) >> 16;                 // v/9
        int dyq = (n * 22) >> 6;                   // n/3
        int dx = n - 3 * dyq - 1, dy = dyq - 1;
        int sy = y + dy, sx = xg + dx;
        bool ok = ((unsigned)sy < 128u) && ((unsigned)sx < 128u);
        int e0 = (c0 & ~1) + 2 * gq;
        size_t gidx = ((size_t)((bI * 128 + (ok ? sy : 0)) * 128 + (ok ? sx : 0))) * 128 + e0;
        gv[r] = ok ? ((const unsigned*)nb)[gidx >> 1] : 0u;
    }
    #pragma unroll
    for (int r = 0; r < 9; ++r) {                  // parity merge (slot15 = zero-wt)
        int v = n2 * 128 + r;
        int c0 = (v * 7282) >> 16;
        unsigned nxt = (unsigned)__shfl_down((int)gv[r], 1);
        if (c0 & 1) gv[r] = (gv[r] >> 16) | (nxt << 16);
    }
}
__device__ __forceinline__ void gather_store(
    USHORT* __restrict__ As, const unsigned gv[9], int gx, int gq)
{
    #pragma unroll
    for (int r = 0; r < 9; ++r)
        *(unsigned*)(As + gx * AW + 16 * r + 2 * gq) = gv[r];
}

// ---------------------------------------------------------------------------
// k_gate: 512 blocks x 512 thr, 64 px/block. wave = col-tile cg (4 drive,
// 4 res), 2 M-tiles each. Emits g10[px][10] bf16 = {g_n/mass x9, sg/mass}.
// MFMA 32x32x16 bf16; C/D: col=lane&31, row=(reg&3)+8*(reg>>2)+4*(lane>>5).
// ---------------------------------------------------------------------------
__global__ __launch_bounds__(512, 2) void k_gate(
    const USHORT* __restrict__ nb,
    const USHORT* __restrict__ WnF, const USHORT* __restrict__ WcF,
    const float* __restrict__ preF, const float* __restrict__ w2g,
    const float* __restrict__ db2p, const float* __restrict__ rb2p,
    const float* __restrict__ gmp, const float* __restrict__ lmp,
    const float* __restrict__ bip, USHORT* __restrict__ g10)
{
    __shared__ char smem[43008];
    USHORT* A0   = (USHORT*)smem;                    // [64][152] = 19456
    USHORT* A1   = (USHORT*)(smem + 19456);          // [64][152] = 19456
    float*  S    = (float*)(smem + 38912);           // [3][128]  = 1536
    float*  gateL= (float*)(smem + 40448);           // [9][64]   = 2304
    float*  sgL  = (float*)(smem + 42752);           // [64]

    const int tid = threadIdx.x;
    const int lane = tid & 63, wave = tid >> 6, hi = lane >> 5, l31 = lane & 31;
    const int gx = tid >> 3, gq = tid & 7;
    const int blk = blockIdx.x;
    const int bI = blk >> 8, bb = blk & 255;
    const int half = bb & 1, yb = bb >> 1;
    const int y = ((yb & 7) << 4) | ((yb >> 3) & 15);     // XCD band swizzle
    const int xg = half * 64 + gx;
    const int px0 = (bI * 128 + y) * 128 + half * 64;

    // ---- stage own 64 px (K natural) -> A1; zero sums ----
    for (int i = tid; i < 1024; i += 512) {
        int x = i >> 4, kv = i & 15;
        *(v8u*)(A1 + x * AW + kv * 8) = *(const v8u*)(nb + (size_t)(px0 + x) * 128 + kv * 8);
    }
    if (tid < 384) S[tid] = 0.f;
    if (tid < 64) sgL[tid] = 0.f;
    __syncthreads();

    // ---- center GEMM (K=128) -> packed bf16 pairs (Mtile0, Mtile1) ----
    const int cg = wave;
    v16f c0a, c1a;
    #pragma unroll
    for (int e = 0; e < 16; ++e) { c0a[e] = 0.f; c1a[e] = 0.f; }
    #pragma unroll
    for (int ks = 0; ks < 8; ++ks) {
        v8bf a0 = *(const v8bf*)(A1 + l31 * AW + ks * 16 + hi * 8);
        v8bf a1 = *(const v8bf*)(A1 + (32 + l31) * AW + ks * 16 + hi * 8);
        v8bf bf = *(const v8bf*)(WcF + ((cg << 3) + ks) * 512 + lane * 8);
        c0a = __builtin_amdgcn_mfma_f32_32x32x16_bf16(a0, bf, c0a, 0, 0, 0);
        c1a = __builtin_amdgcn_mfma_f32_32x32x16_bf16(a1, bf, c1a, 0, 0, 0);
    }
    unsigned cpk[16];
    #pragma unroll
    for (int e = 0; e < 16; ++e)
        cpk[e] = (unsigned)f2bf(c0a[e]) | ((unsigned)f2bf(c1a[e]) << 16);

    {   // first gather -> A0
        unsigned gv[9];
        gather_load(gv, nb, 0, y, xg, bI, gq);
        gather_store(A0, gv, gx, gq);
    }
    // persistent B-frags (n2-invariant): 9 x 4 VGPR
    v8bf Bp[9];
    #pragma unroll
    for (int ks = 0; ks < 9; ++ks)
        Bp[ks] = *(const v8bf*)(WnF + (cg * 9 + ks) * 512 + lane * 8);
    __syncthreads();

    const float gmv = gmp[0], lmv = lmp[0], biv = bip[0];
    const float db2v = db2p[0], rb2v = rb2p[0];
    const float wv = w2g[cg * 32 + l31];
    const int tgt_off = (cg >= 4) ? 64 : 0;
    const int rbase = 4 * hi;

    for (int n2 = 0; n2 < 9; ++n2) {
        const float pre = preF[n2 * 256 + cg * 32 + l31];
        unsigned gv[9];
        if (n2 < 8) gather_load(gv, nb, n2 + 1, y, xg, bI, gq);

        USHORT* Ac = (n2 & 1) ? A1 : A0;
        USHORT* An = (n2 & 1) ? A0 : A1;
        v16f ad0, ad1;
        #pragma unroll
        for (int e = 0; e < 16; ++e) { ad0[e] = 0.f; ad1[e] = 0.f; }
        #pragma unroll
        for (int ks = 0; ks < 9; ++ks) {
            v8bf a0 = *(const v8bf*)(Ac + l31 * AW + ks * 16 + hi * 8);
            v8bf a1 = *(const v8bf*)(Ac + (32 + l31) * AW + ks * 16 + hi * 8);
            ad0 = __builtin_amdgcn_mfma_f32_32x32x16_bf16(a0, Bp[ks], ad0, 0, 0, 0);
            ad1 = __builtin_amdgcn_mfma_f32_32x32x16_bf16(a1, Bp[ks], ad1, 0, 0, 0);
        }
        float* Sset = S + (n2 % 3) * 128 + tgt_off;
        #pragma unroll
        for (int c4 = 0; c4 < 4; ++c4) {
            float z4[4];
            #pragma unroll
            for (int k4 = 0; k4 < 4; ++k4) {
                int rr = c4 * 4 + k4;
                float h0 = ad0[rr] + pre + bflo(cpk[rr]);
                float h1 = ad1[rr] + pre + bfhi(cpk[rr]);
                float p0 = h0 * __builtin_amdgcn_rcpf(1.f + __expf(-1.702f * h0)) * wv;
                float p1 = h1 * __builtin_amdgcn_rcpf(1.f + __expf(-1.702f * h1)) * wv;
                float sa = p0 + __shfl_xor(p0, 1);     // even lanes: M-tile0
                float sb = p1 + __shfl_xor(p1, 1);     // odd lanes:  M-tile1
                z4[k4] = (l31 & 1) ? sb : sa;
            }
            #pragma unroll
            for (int m = 2; m < 32; m <<= 1) {
                #pragma unroll
                for (int k4 = 0; k4 < 4; ++k4) z4[k4] += __shfl_xor(z4[k4], m);
            }
            if (l31 < 2) {
                int rb = rbase + 8 * c4 + ((l31 == 1) ? 32 : 0);
                #pragma unroll
                for (int k4 = 0; k4 < 4; ++k4)
                    atomicAdd(&Sset[rb + k4], z4[k4]);
            }
        }
        if (n2 < 8) gather_store(An, gv, gx, gq);
        __syncthreads();
        // gates (wave0) + zero set 2-ahead (threads 64..191)
        if (tid < 64) {
            float d = S[(n2 % 3) * 128 + tid] + db2v;
            float r = S[(n2 % 3) * 128 + 64 + tid] + rb2v;
            float sp = fmaxf(r, 0.f) + log1pf(__expf(-fabsf(r)));
            float e = gmv * d / (lmv * sp + 1e-6f) + biv;
            e = fminf(fmaxf(e, -3.f), 3.f);
            float gt = 1.f / (1.f + __expf(-e));
            gateL[n2 * 64 + tid] = gt;
            sgL[tid] += gt;
        } else if (tid < 192) {
            S[((n2 + 2) % 3) * 128 + tid - 64] = 0.f;
        }
    }
    __syncthreads();

    if (tid < 64) {
        float s = sgL[tid];
        float m = fmaxf(s, 1e-6f);
        S[tid] = 1.f / m;                 // 1/mass
        S[64 + tid] = s / m;              // sg/mass
    }
    __syncthreads();
    for (int i = tid; i < 640; i += 512) {
        int px = (i * 6554) >> 16;        // i/10
        int n = i - px * 10;
        float val = (n < 9) ? gateL[n * 64 + px] * S[px] : S[64 + px];
        g10[(size_t)(px0 + px) * 10 + n] = f2bf(val);
    }
}

// ---------------------------------------------------------------------------
// k_msg: 512 blocks x 512 thr, 64 px/block. wave = (mwp, nwp): 2M x 4N.
// acc3 = Sum_n (g_n/mass)(A_n @ VoW); update + fused LN2.
// ---------------------------------------------------------------------------
__global__ __launch_bounds__(512, 2) void k_msg(
    const float* __restrict__ tok, const float* __restrict__ ln2g,
    const float* __restrict__ ln2b, const USHORT* __restrict__ nb,
    const USHORT* __restrict__ VF, const float* __restrict__ vboW,
    const float* __restrict__ obp, const USHORT* __restrict__ g10,
    float* __restrict__ out)
{
    __shared__ char smem[41472];
    USHORT* A0   = (USHORT*)smem;                    // [64][152] = 19456
    USHORT* A1   = (USHORT*)(smem + 19456);          // [64][152] = 19456
    float*  gL   = (float*)(smem + 38912);           // [9][64] gates + [64] sgm
    float*  updF = (float*)smem;                     // tail alias [64][128] f32

    const int tid = threadIdx.x;
    const int lane = tid & 63, wave = tid >> 6, hi = lane >> 5, l31 = lane & 31;
    const int mwp = wave & 1, nwp = wave >> 1;
    const int gx = tid >> 3, gq = tid & 7;
    const int blk = blockIdx.x;
    const int bI = blk >> 8, bb = blk & 255;
    const int half = bb & 1, yb = bb >> 1;
    const int y = ((yb & 7) << 4) | ((yb >> 3) & 15);
    const int xg = half * 64 + gx;
    const int px0 = (bI * 128 + y) * 128 + half * 64;

    // ---- stage gates + first gather ----
    for (int i = tid; i < 640; i += 512) {
        int px = (i * 6554) >> 16;
        int n = i - px * 10;
        gL[n * 64 + px] = bflo((unsigned)g10[(size_t)(px0 + px) * 10 + n]);
    }
    {
        unsigned gv[9];
        gather_load(gv, nb, 0, y, xg, bI, gq);
        gather_store(A0, gv, gx, gq);
    }
    v8bf Vp[9];
    #pragma unroll
    for (int ks = 0; ks < 9; ++ks)
        Vp[ks] = *(const v8bf*)(VF + (nwp * 9 + ks) * 512 + lane * 8);
    __syncthreads();

    v16f acc3;
    #pragma unroll
    for (int e = 0; e < 16; ++e) acc3[e] = 0.f;

    for (int m2 = 0; m2 < 9; ++m2) {
        unsigned gv[9];
        if (m2 < 8) gather_load(gv, nb, m2 + 1, y, xg, bI, gq);
        USHORT* Ac = (m2 & 1) ? A1 : A0;
        USHORT* An = (m2 & 1) ? A0 : A1;
        v16f am;
        #pragma unroll
        for (int e = 0; e < 16; ++e) am[e] = 0.f;
        #pragma unroll
        for (int ks = 0; ks < 9; ++ks) {
            v8bf a = *(const v8bf*)(Ac + (mwp * 32 + l31) * AW + ks * 16 + hi * 8);
            am = __builtin_amdgcn_mfma_f32_32x32x16_bf16(a, Vp[ks], am, 0, 0, 0);
        }
        {   // acc3 += (g/mass)(m2) ⊙ am
            const float4* gq4 = (const float4*)(gL + m2 * 64 + mwp * 32 + 4 * hi);
            float4 ga = gq4[0], gb = gq4[2], gc = gq4[4], gd = gq4[6];
            float gs[16] = {ga.x, ga.y, ga.z, ga.w, gb.x, gb.y, gb.z, gb.w,
                            gc.x, gc.y, gc.z, gc.w, gd.x, gd.y, gd.z, gd.w};
            #pragma unroll
            for (int rr = 0; rr < 16; ++rr) acc3[rr] += gs[rr] * am[rr];
        }
        if (m2 < 8) gather_store(An, gv, gx, gq);
        __syncthreads();
    }

    // ---- update + LN2 ----
    {
        const int col = nwp * 32 + l31;
        const float vbw = vboW[col], obv = obp[col];
        const int base = mwp * 32 + 4 * hi;
        const float4* sq = (const float4*)(gL + 576 + base);
        float4 sa = sq[0], sb = sq[2], sc = sq[4], sd = sq[6];
        float sv[16] = {sa.x, sa.y, sa.z, sa.w, sb.x, sb.y, sb.z, sb.w,
                        sc.x, sc.y, sc.z, sc.w, sd.x, sd.y, sd.z, sd.w};
        #pragma unroll
        for (int rr = 0; rr < 16; ++rr) {
            int row = base + (rr & 3) + 8 * (rr >> 2);
            updF[row * 128 + col] = acc3[rr] + vbw * sv[rr] + obv;
        }
    }
    __syncthreads();

    const float g20 = ln2g[lane], g21 = ln2g[lane + 64];
    const float b20 = ln2b[lane], b21 = ln2b[lane + 64];
    for (int q2 = 0; q2 < 8; ++q2) {
        int p = wave * 8 + q2;
        size_t gp = (size_t)(px0 + p) * 128;
        float x0 = tok[gp + lane]      + updF[p * 128 + lane];
        float x1 = tok[gp + lane + 64] + updF[p * 128 + lane + 64];
        float s = x0 + x1;
        for (int m = 1; m < 64; m <<= 1) s += __shfl_xor(s, m);
        float mean = s * (1.f / 128.f);
        float d0 = x0 - mean, d1 = x1 - mean;
        float qq = d0 * d0 + d1 * d1;
        for (int m = 1; m < 64; m <<= 1) qq += __shfl_xor(qq, m);
        float rstd = rsqrtf(qq * (1.f / 128.f) + 1e-5f);
        out[gp + lane]      = d0 * rstd * g20 + b20;
        out[gp + lane + 64] = d1 * rstd * g21 + b21;
    }
}

// ---------------------------------------------------------------------------
extern "C" void kernel_launch(void* const* d_in, const int* in_sizes, int n_in,
                              void* d_out, int out_size, void* d_ws, size_t ws_size,
                              hipStream_t stream) {
    const float* tok  = (const float*)d_in[0];
    const float* ln1g = (const float*)d_in[1];
    const float* ln1b = (const float*)d_in[2];
    const float* ln2g = (const float*)d_in[3];
    const float* ln2b = (const float*)d_in[4];
    const float* rel  = (const float*)d_in[5];
    const float* dW1  = (const float*)d_in[6];
    const float* db1  = (const float*)d_in[7];
    const float* dW2  = (const float*)d_in[8];
    const float* db2  = (const float*)d_in[9];
    const float* rW1  = (const float*)d_in[10];
    const float* rb1  = (const float*)d_in[11];
    const float* rW2  = (const float*)d_in[12];
    const float* rb2  = (const float*)d_in[13];
    const float* vW   = (const float*)d_in[14];
    const float* vb   = (const float*)d_in[15];
    const float* oW   = (const float*)d_in[16];
    const float* ob   = (const float*)d_in[17];
    const float* gm   = (const float*)d_in[18];
    const float* lm   = (const float*)d_in[19];
    const float* bi   = (const float*)d_in[20];
    float* out = (float*)d_out;

    char* w = (char*)d_ws;
    USHORT* norm = (USHORT*)w; w += 8388608;   // [32768][128] bf16
    USHORT* WnF  = (USHORT*)w; w += 73728;     // [72 frag-blocks][512] bf16
    USHORT* WcF  = (USHORT*)w; w += 65536;     // [64][512]
    USHORT* VF   = (USHORT*)w; w += 36864;     // [36][512]
    USHORT* g10  = (USHORT*)w; w += 655360;    // [32768][10] bf16 (g/mass, sgm)
    float*  preF = (float*)w;  w += 9216;      // [9][256] f32
    float*  vboW = (float*)w;  w += 512;       // [128]
    float*  w2g  = (float*)w;  w += 1024;      // [256]

    hipLaunchKernelGGL(k_setup, dim3(1206), dim3(256), 0, stream,
                       tok, ln1g, ln1b, dW1, db1, rW1, rb1, rel, dW2, rW2,
                       vW, vb, oW, norm, WnF, WcF, VF, preF, vboW, w2g);
    hipLaunchKernelGGL(k_gate, dim3(512), dim3(512), 0, stream,
                       norm, WnF, WcF, preF, w2g, db2, rb2, gm, lm, bi, g10);
    hipLaunchKernelGGL(k_msg, dim3(512), dim3(512), 0, stream,
                       tok, ln2g, ln2b, norm, VF, vboW, ob, g10, out);
}